// Round 1
// baseline (886.557 us; speedup 1.0000x reference)
//
#include <hip/hip_runtime.h>

#define H_ 128
#define W_ 128
#define HW_ (H_ * W_)
#define B_ 4

// Kernel 1: avg_flow channels + zero-init of iwe channels.
// One thread per (b, c in {0,1}, pixel) over flow layout [B,2,H,W].
__global__ void avgflow_zero_kernel(const float* __restrict__ flow,
                                    const float* __restrict__ event_mask,
                                    float* __restrict__ out) {
    int idx = blockIdx.x * blockDim.x + threadIdx.x;
    if (idx >= B_ * 2 * HW_) return;
    int b   = idx / (2 * HW_);
    int r   = idx - b * (2 * HW_);
    int c   = r / HW_;           // flow channel 0/1
    int pix = r - c * HW_;
    float m = event_mask[b * HW_ + pix];
    float f = flow[idx];
    float* ob = out + (size_t)b * 4 * HW_;
    ob[(2 + c) * HW_ + pix] = f * m / (m + 1e-9f);  // avg_flow channel
    ob[c * HW_ + pix]       = 0.0f;                 // zero iwe channel
}

// Kernel 2: per-event warp + bilinear scatter-add.
__global__ void event_scatter_kernel(const float* __restrict__ event_list,
                                     const float* __restrict__ flow,
                                     float* __restrict__ out, int nN) {
    int gid = blockIdx.x * blockDim.x + threadIdx.x;
    int total = B_ * nN;
    if (gid >= total) return;
    int b = gid / nN;

    float4 ev = reinterpret_cast<const float4*>(event_list)[gid];
    float ts = ev.x, y = ev.y, x = ev.z, p = ev.w;

    // flow gather at rounded event position (round-half-even = jnp.round)
    int py = __float2int_rn(y);
    int px = __float2int_rn(x);
    int pidx = py * W_ + px;
    pidx = max(0, min(HW_ - 1, pidx));   // defensive clamp (XLA clamps too)

    const float* fb = flow + (size_t)b * 2 * HW_;
    float fx = fb[pidx];          // flow channel 0 (x-flow)
    float fy = fb[HW_ + pidx];    // flow channel 1 (y-flow)

    float rts = 1.0f - ts;
    float wy = y + rts * fy;      // warped y  (event_flow[...,0] = flow ch1)
    float wx = x + rts * fx;      // warped x  (event_flow[...,1] = flow ch0)

    float ty = floorf(wy);
    float lx = floorf(wx);
    float fyf = wy - ty;          // weight of bottom row
    float fxf = wx - lx;          // weight of right col
    int ity = (int)ty, ilx = (int)lx;

    float wrow[2] = {1.0f - fyf, fyf};
    float wcol[2] = {1.0f - fxf, fxf};

    int ch = (p > 0.5f) ? 0 : 1;  // pos channel gets w*p, neg gets w*(1-p)
    float* ob = out + (size_t)b * 4 * HW_ + ch * HW_;

    #pragma unroll
    for (int dy = 0; dy < 2; ++dy) {
        int cy = ity + dy;
        if (cy < 0 || cy >= H_) continue;
        #pragma unroll
        for (int dx = 0; dx < 2; ++dx) {
            int cx = ilx + dx;
            if (cx < 0 || cx >= W_) continue;
            float w = wrow[dy] * wcol[dx];
            atomicAdd(ob + cy * W_ + cx, w);
        }
    }
}

extern "C" void kernel_launch(void* const* d_in, const int* in_sizes, int n_in,
                              void* d_out, int out_size, void* d_ws, size_t ws_size,
                              hipStream_t stream) {
    const float* flow       = (const float*)d_in[0];  // [B,2,H,W]
    const float* event_list = (const float*)d_in[1];  // [B,N,4]
    // d_in[2] = pol_mask — redundant, pol_mask = [p, 1-p] from event_list
    const float* event_mask = (const float*)d_in[3];  // [B,1,H,W]
    float* out = (float*)d_out;                       // [B,4,H,W]

    int nN = in_sizes[1] / (B_ * 4);                  // events per batch

    int n1 = B_ * 2 * HW_;
    avgflow_zero_kernel<<<(n1 + 255) / 256, 256, 0, stream>>>(flow, event_mask, out);

    int total = B_ * nN;
    event_scatter_kernel<<<(total + 255) / 256, 256, 0, stream>>>(event_list, flow, out, nN);
}

// Round 4
// 201.830 us; speedup vs baseline: 4.3926x; 4.3926x over previous
//
#include <hip/hip_runtime.h>

#define H_ 128
#define W_ 128
#define HW_ (H_ * W_)
#define B_ 4
#define CH2_ (2 * HW_)   // 32768 floats = 128 KB (one per-batch 2-channel histogram)

// Kernel 1: per-block LDS-privatized event histogram.
// Grid = B_ * bpb blocks; block (b, j) processes events [j*cs, (j+1)*cs) of
// batch b into a full [2][H][W] f32 LDS histogram, then dumps the partial to
// workspace with plain coalesced stores (NO global atomics).
__global__ __launch_bounds__(1024)
void event_hist_kernel(const float* __restrict__ event_list,
                       const float* __restrict__ flow,
                       float* __restrict__ ws,
                       int nN, int bpb, int cs) {
    __shared__ float hist[CH2_];   // 128 KB
    int tid = threadIdx.x;
    #pragma unroll
    for (int i = tid; i < CH2_; i += 1024) hist[i] = 0.0f;
    __syncthreads();

    int b = blockIdx.x / bpb;
    int j = blockIdx.x - b * bpb;
    int start = j * cs;
    int end = min(nN, start + cs);

    const float4* evb = reinterpret_cast<const float4*>(event_list) + (size_t)b * nN;
    const float* fb = flow + (size_t)b * CH2_;   // [2][H][W] for batch b (L2-resident)

    for (int i = start + tid; i < end; i += 1024) {
        float4 ev = evb[i];
        float ts = ev.x, y = ev.y, x = ev.z, p = ev.w;

        // flow gather at rounded event position (round-half-even = jnp.round)
        int py = __float2int_rn(y);
        int px = __float2int_rn(x);
        int pidx = py * W_ + px;
        pidx = max(0, min(HW_ - 1, pidx));
        float fx = fb[pidx];          // flow channel 0 (x)
        float fy = fb[HW_ + pidx];    // flow channel 1 (y)

        float rts = 1.0f - ts;
        float wy = fmaf(rts, fy, y);  // warped y
        float wx = fmaf(rts, fx, x);  // warped x

        float tyf = floorf(wy), lxf = floorf(wx);
        float fyf = wy - tyf;         // bottom-row weight
        float fxf = wx - lxf;         // right-col weight
        int ity = (int)tyf, ilx = (int)lxf;

        int ch = (p > 0.5f) ? 0 : 1;  // pos events -> channel 0, neg -> channel 1
        float* hch = hist + ch * HW_;

        float wr0 = 1.0f - fyf, wr1 = fyf;
        float wc0 = 1.0f - fxf, wc1 = fxf;

        bool y0 = (ity >= 0) & (ity < H_);
        bool y1 = (ity + 1 >= 0) & (ity + 1 < H_);
        bool x0 = (ilx >= 0) & (ilx < W_);
        bool x1 = (ilx + 1 >= 0) & (ilx + 1 < W_);

        if (y0 & x0) atomicAdd(hch + ity * W_ + ilx,           wr0 * wc0);
        if (y0 & x1) atomicAdd(hch + ity * W_ + ilx + 1,       wr0 * wc1);
        if (y1 & x0) atomicAdd(hch + (ity + 1) * W_ + ilx,     wr1 * wc0);
        if (y1 & x1) atomicAdd(hch + (ity + 1) * W_ + ilx + 1, wr1 * wc1);
    }
    __syncthreads();

    // Dump partial histogram: ws layout [B][bpb][2][HW], coalesced float4.
    float* wsb = ws + (size_t)blockIdx.x * CH2_;
    #pragma unroll
    for (int i = tid; i < CH2_ / 4; i += 1024)
        reinterpret_cast<float4*>(wsb)[i] =
            reinterpret_cast<const float4*>(hist)[i];
}

// Kernel 2: reduce bpb partials per (b, ch, pix) + fused avg_flow pass.
__global__ void reduce_kernel(const float* __restrict__ ws,
                              const float* __restrict__ flow,
                              const float* __restrict__ event_mask,
                              float* __restrict__ out, int bpb) {
    int idx = blockIdx.x * blockDim.x + threadIdx.x;
    if (idx >= B_ * CH2_) return;
    int b = idx / CH2_;
    int r = idx - b * CH2_;            // r = ch*HW + pix

    const float* base = ws + (size_t)b * bpb * CH2_ + r;
    float s = 0.0f;
    for (int j = 0; j < bpb; ++j) s += base[(size_t)j * CH2_];

    int ch  = r / HW_;
    int pix = r - ch * HW_;
    float* ob = out + (size_t)b * 4 * HW_;
    ob[ch * HW_ + pix] = s;                          // iwe channel

    float m = event_mask[b * HW_ + pix];
    float f = flow[(size_t)b * CH2_ + r];
    ob[(2 + ch) * HW_ + pix] = f * m / (m + 1e-9f);  // avg_flow channel
}

extern "C" void kernel_launch(void* const* d_in, const int* in_sizes, int n_in,
                              void* d_out, int out_size, void* d_ws, size_t ws_size,
                              hipStream_t stream) {
    const float* flow       = (const float*)d_in[0];  // [B,2,H,W]
    const float* event_list = (const float*)d_in[1];  // [B,N,4]
    const float* event_mask = (const float*)d_in[3];  // [B,1,H,W]
    float* out = (float*)d_out;                       // [B,4,H,W]
    float* ws  = (float*)d_ws;

    int nN = in_sizes[1] / (B_ * 4);                  // events per batch

    // partials need B*bpb*CH2_*4 bytes; shrink bpb if workspace is small
    int bpb = 64;
    while (bpb > 1 && (size_t)B_ * bpb * CH2_ * 4 > ws_size) bpb >>= 1;
    int cs = (nN + bpb - 1) / bpb;                    // events per block

    event_hist_kernel<<<B_ * bpb, 1024, 0, stream>>>(event_list, flow, ws, nN, bpb, cs);

    int n2 = B_ * CH2_;
    reduce_kernel<<<(n2 + 255) / 256, 256, 0, stream>>>(ws, flow, event_mask, out, bpb);
}

// Round 6
// 196.773 us; speedup vs baseline: 4.5055x; 1.0257x over previous
//
#include <hip/hip_runtime.h>

#define H_ 128
#define W_ 128
#define HW_ (H_ * W_)
#define B_ 4
#define CH2_ (2 * HW_)   // 32768 floats = 128 KB (one per-batch 2-channel histogram)
#define NT_ 1024

// Process one event into the LDS histogram.
__device__ __forceinline__ void scatter_event(float4 ev, float fx, float fy,
                                              float* hist) {
    float rts = 1.0f - ev.x;          // (1 - ts)
    float wy = fmaf(rts, fy, ev.y);   // warped y  (event_flow[...,0] = flow ch1)
    float wx = fmaf(rts, fx, ev.z);   // warped x  (event_flow[...,1] = flow ch0)

    float tyf = floorf(wy), lxf = floorf(wx);
    float fyf = wy - tyf;             // bottom-row weight
    float fxf = wx - lxf;             // right-col weight
    int ity = (int)tyf, ilx = (int)lxf;

    int ch = (ev.w > 0.5f) ? 0 : 1;   // pos -> channel 0, neg -> channel 1
    float* hch = hist + ch * HW_;

    float wr0 = 1.0f - fyf, wr1 = fyf;
    float wc0 = 1.0f - fxf, wc1 = fxf;

    bool y0 = (ity >= 0) & (ity < H_);
    bool y1 = (ity + 1 >= 0) & (ity + 1 < H_);
    bool x0 = (ilx >= 0) & (ilx < W_);
    bool x1 = (ilx + 1 >= 0) & (ilx + 1 < W_);

    if (y0 & x0) atomicAdd(hch + ity * W_ + ilx,           wr0 * wc0);
    if (y0 & x1) atomicAdd(hch + ity * W_ + ilx + 1,       wr0 * wc1);
    if (y1 & x0) atomicAdd(hch + (ity + 1) * W_ + ilx,     wr1 * wc0);
    if (y1 & x1) atomicAdd(hch + (ity + 1) * W_ + ilx + 1, wr1 * wc1);
}

// Kernel 1: per-block LDS-privatized event histogram, 4x ILP-unrolled.
// 1 block/CU (128 KB LDS); __launch_bounds__(1024,4) allows up to 128 VGPR.
__global__ __launch_bounds__(NT_, 4)
void event_hist_kernel(const float* __restrict__ event_list,
                       const float* __restrict__ flow,
                       float* __restrict__ ws,
                       int nN, int bpb, int cs) {
    __shared__ float hist[CH2_];   // 128 KB
    int tid = threadIdx.x;
    #pragma unroll
    for (int i = tid; i < CH2_; i += NT_) hist[i] = 0.0f;
    __syncthreads();

    int b = blockIdx.x / bpb;
    int j = blockIdx.x - b * bpb;
    int start = j * cs;
    int end = min(nN, start + cs);

    const float4* evb = reinterpret_cast<const float4*>(event_list) + (size_t)b * nN;
    const float* fb = flow + (size_t)b * CH2_;   // [2][H][W] for batch b (L2-resident)

    int i = start + tid;
    // main loop: 4 events per iteration, phased for memory-level parallelism
    for (; i + 3 * NT_ < end; i += 4 * NT_) {
        float4 ev[4];
        #pragma unroll
        for (int u = 0; u < 4; ++u) ev[u] = evb[i + u * NT_];   // 4 indep loads

        float fxv[4], fyv[4];
        #pragma unroll
        for (int u = 0; u < 4; ++u) {                            // 8 indep gathers
            int py = __float2int_rn(ev[u].y);
            int px = __float2int_rn(ev[u].z);
            int pidx = py * W_ + px;
            pidx = max(0, min(HW_ - 1, pidx));
            fxv[u] = fb[pidx];          // flow channel 0 (x)
            fyv[u] = fb[HW_ + pidx];    // flow channel 1 (y)
        }

        #pragma unroll
        for (int u = 0; u < 4; ++u)
            scatter_event(ev[u], fxv[u], fyv[u], hist);
    }
    // tail
    for (; i < end; i += NT_) {
        float4 ev = evb[i];
        int py = __float2int_rn(ev.y);
        int px = __float2int_rn(ev.z);
        int pidx = max(0, min(HW_ - 1, py * W_ + px));
        scatter_event(ev, fb[pidx], fb[HW_ + pidx], hist);
    }
    __syncthreads();

    // Dump partial histogram: ws layout [B][bpb][2][HW], coalesced float4.
    float* wsb = ws + (size_t)blockIdx.x * CH2_;
    #pragma unroll
    for (int i2 = tid; i2 < CH2_ / 4; i2 += NT_)
        reinterpret_cast<float4*>(wsb)[i2] =
            reinterpret_cast<const float4*>(hist)[i2];
}

// Kernel 2: reduce bpb partials per (b, ch, pix) + fused avg_flow pass.
__global__ void reduce_kernel(const float* __restrict__ ws,
                              const float* __restrict__ flow,
                              const float* __restrict__ event_mask,
                              float* __restrict__ out, int bpb) {
    int idx = blockIdx.x * blockDim.x + threadIdx.x;
    if (idx >= B_ * CH2_) return;
    int b = idx / CH2_;
    int r = idx - b * CH2_;            // r = ch*HW + pix

    const float* base = ws + (size_t)b * bpb * CH2_ + r;
    float s = 0.0f;
    #pragma unroll 8
    for (int j = 0; j < bpb; ++j) s += base[(size_t)j * CH2_];

    int ch  = r / HW_;
    int pix = r - ch * HW_;
    float* ob = out + (size_t)b * 4 * HW_;
    ob[ch * HW_ + pix] = s;                          // iwe channel

    float m = event_mask[b * HW_ + pix];
    float f = flow[(size_t)b * CH2_ + r];
    ob[(2 + ch) * HW_ + pix] = f * m / (m + 1e-9f);  // avg_flow channel
}

extern "C" void kernel_launch(void* const* d_in, const int* in_sizes, int n_in,
                              void* d_out, int out_size, void* d_ws, size_t ws_size,
                              hipStream_t stream) {
    const float* flow       = (const float*)d_in[0];  // [B,2,H,W]
    const float* event_list = (const float*)d_in[1];  // [B,N,4]
    const float* event_mask = (const float*)d_in[3];  // [B,1,H,W]
    float* out = (float*)d_out;                       // [B,4,H,W]
    float* ws  = (float*)d_ws;

    int nN = in_sizes[1] / (B_ * 4);                  // events per batch

    // partials need B*bpb*CH2_*4 bytes; shrink bpb if workspace is small
    int bpb = 64;
    while (bpb > 1 && (size_t)B_ * bpb * CH2_ * 4 > ws_size) bpb >>= 1;
    int cs = (nN + bpb - 1) / bpb;                    // events per block

    event_hist_kernel<<<B_ * bpb, NT_, 0, stream>>>(event_list, flow, ws, nN, bpb, cs);

    int n2 = B_ * CH2_;
    reduce_kernel<<<(n2 + 255) / 256, 256, 0, stream>>>(ws, flow, event_mask, out, bpb);
}